// Round 1
// baseline (988.853 us; speedup 1.0000x reference)
//
#include <hip/hip_runtime.h>

namespace {

constexpr int N    = 40000;
constexpr int E    = 640000;
constexpr int DIM  = 128;
constexpr int NG   = 256;
constexpr int OUTC = 16;
constexpr float BN_EPS = 1e-5f;

__device__ __forceinline__ void atomAddF(float* p, float v) {
  unsafeAtomicAdd(p, v);  // global_atomic_add_f32 on gfx950
}

// ---------------- CSR build ----------------

__global__ void zero_ints(int* __restrict__ p, int n) {
  int i = blockIdx.x * blockDim.x + threadIdx.x;
  if (i < n) p[i] = 0;
}

__global__ void hist_kernel(const int* __restrict__ dst, int* __restrict__ deg) {
  int e = blockIdx.x * blockDim.x + threadIdx.x;
  if (e < E) atomicAdd(&deg[dst[e]], 1);
}

__global__ __launch_bounds__(1024) void scan_kernel(const int* __restrict__ deg,
                                                    int* __restrict__ rp) {
  constexpr int CH = (N + 1023) / 1024;  // 40
  const int t = threadIdx.x;
  const int beg = t * CH;
  const int end = (beg + CH < N) ? (beg + CH) : N;
  int s = 0;
  for (int i = beg; i < end; ++i) s += deg[i];
  __shared__ int sums[1024];
  sums[t] = s;
  __syncthreads();
  for (int off = 1; off < 1024; off <<= 1) {
    int v = (t >= off) ? sums[t - off] : 0;
    __syncthreads();
    sums[t] += v;
    __syncthreads();
  }
  int run = (t == 0) ? 0 : sums[t - 1];  // exclusive prefix
  for (int i = beg; i < end; ++i) { rp[i] = run; run += deg[i]; }
  if (t == 1023) rp[N] = run;  // == E
}

__global__ void copy_ints(const int* __restrict__ a, int* __restrict__ b, int n) {
  int i = blockIdx.x * blockDim.x + threadIdx.x;
  if (i < n) b[i] = a[i];
}

__global__ void fill_kernel(const int* __restrict__ src, const int* __restrict__ dst,
                            int* __restrict__ cursor, int* __restrict__ col) {
  int e = blockIdx.x * blockDim.x + threadIdx.x;
  if (e < E) {
    int p = atomicAdd(&cursor[dst[e]], 1);
    col[p] = src[e];
  }
}

// ---------------- GIN aggregation: t = xin + sum_{j in N(i)} xin[j] ----------------
// One 32-lane group per node, float4 per lane (128 ch = 32 lanes * 4).

__global__ __launch_bounds__(256) void aggregate_kernel(const float* __restrict__ xin,
                                                        const int* __restrict__ rp,
                                                        const int* __restrict__ col,
                                                        float* __restrict__ t) {
  const int g    = (blockIdx.x * blockDim.x + threadIdx.x) >> 5;  // node
  const int lane = threadIdx.x & 31;
  if (g >= N) return;
  const float4* __restrict__ x4 = (const float4*)xin;
  float4 acc = x4[(size_t)g * 32 + lane];
  const int b = rp[g], e = rp[g + 1];
  for (int k = b; k < e; ++k) {
    int j = col[k];
    float4 v = x4[(size_t)j * 32 + lane];
    acc.x += v.x; acc.y += v.y; acc.z += v.z; acc.w += v.w;
  }
  ((float4*)t)[(size_t)g * 32 + lane] = acc;
}

// ---------------- GEMM [N,128] @ [128,128]  (one wave per 64 rows x 32 cols) ------
// W addressed block-uniformly -> scalar loads (SGPR broadcast), zero LDS.
// PRO: apply BN scale/shift + relu to A on load.  RELU: relu on output.

template <int PRO, int RELU>
__global__ __launch_bounds__(64) void gemm_k(const float* __restrict__ A,
                                             const float* __restrict__ W,
                                             const float* __restrict__ bias,
                                             const float* __restrict__ scsh,
                                             float* __restrict__ out) {
  const int lane = threadIdx.x;                 // 0..63
  const int rb   = blockIdx.x >> 2;             // 0..624
  const int c0   = (blockIdx.x & 3) * 32;       // col slice
  const int row  = rb * 64 + lane;              // 40000 = 625*64 exactly
  const float* __restrict__ arow = A + (size_t)row * DIM;

  float acc[32];
#pragma unroll
  for (int j = 0; j < 32; ++j) acc[j] = 0.f;

  for (int k = 0; k < DIM; k += 4) {
    float4 a4 = *(const float4*)(arow + k);
    if (PRO) {
      float4 sc = *(const float4*)(scsh + k);
      float4 sh = *(const float4*)(scsh + DIM + k);
      a4.x = fmaxf(fmaf(a4.x, sc.x, sh.x), 0.f);
      a4.y = fmaxf(fmaf(a4.y, sc.y, sh.y), 0.f);
      a4.z = fmaxf(fmaf(a4.z, sc.z, sh.z), 0.f);
      a4.w = fmaxf(fmaf(a4.w, sc.w, sh.w), 0.f);
    }
    const float aa[4] = {a4.x, a4.y, a4.z, a4.w};
#pragma unroll
    for (int kk = 0; kk < 4; ++kk) {
      const float* __restrict__ wr = W + (size_t)(k + kk) * DIM + c0;
#pragma unroll
      for (int j = 0; j < 32; ++j) acc[j] = fmaf(aa[kk], wr[j], acc[j]);
    }
  }

#pragma unroll
  for (int j = 0; j < 32; j += 4) {
    float4 v;
    v.x = acc[j + 0] + bias[c0 + j + 0];
    v.y = acc[j + 1] + bias[c0 + j + 1];
    v.z = acc[j + 2] + bias[c0 + j + 2];
    v.w = acc[j + 3] + bias[c0 + j + 3];
    if (RELU) {
      v.x = fmaxf(v.x, 0.f); v.y = fmaxf(v.y, 0.f);
      v.z = fmaxf(v.z, 0.f); v.w = fmaxf(v.w, 0.f);
    }
    *(float4*)(out + (size_t)row * DIM + c0 + j) = v;
  }
}

// ---------------- BatchNorm statistics: per-channel sum & sumsq over N rows -------

__global__ __launch_bounds__(256) void bn_stats_kernel(const float* __restrict__ h,
                                                       float* __restrict__ stats) {
  const int tid = threadIdx.x;
  const int c4  = tid & 31;   // float4 column group
  const int sub = tid >> 5;   // 0..7
  float4 s = {0, 0, 0, 0}, q = {0, 0, 0, 0};
  for (int r = blockIdx.x * 8 + sub; r < N; r += 256 * 8) {
    float4 v = ((const float4*)h)[(size_t)r * 32 + c4];
    s.x += v.x; s.y += v.y; s.z += v.z; s.w += v.w;
    q.x = fmaf(v.x, v.x, q.x); q.y = fmaf(v.y, v.y, q.y);
    q.z = fmaf(v.z, v.z, q.z); q.w = fmaf(v.w, v.w, q.w);
  }
  __shared__ float red[256 * 4];
  // --- reduce sums ---
  red[tid * 4 + 0] = s.x; red[tid * 4 + 1] = s.y;
  red[tid * 4 + 2] = s.z; red[tid * 4 + 3] = s.w;
  __syncthreads();
  for (int st = 128; st >= 32; st >>= 1) {
    if (tid < st) {
#pragma unroll
      for (int i = 0; i < 4; ++i) red[tid * 4 + i] += red[(tid + st) * 4 + i];
    }
    __syncthreads();
  }
  if (tid < 32) {
#pragma unroll
    for (int i = 0; i < 4; ++i) atomAddF(&stats[tid * 4 + i], red[tid * 4 + i]);
  }
  __syncthreads();
  // --- reduce sum of squares ---
  red[tid * 4 + 0] = q.x; red[tid * 4 + 1] = q.y;
  red[tid * 4 + 2] = q.z; red[tid * 4 + 3] = q.w;
  __syncthreads();
  for (int st = 128; st >= 32; st >>= 1) {
    if (tid < st) {
#pragma unroll
      for (int i = 0; i < 4; ++i) red[tid * 4 + i] += red[(tid + st) * 4 + i];
    }
    __syncthreads();
  }
  if (tid < 32) {
#pragma unroll
    for (int i = 0; i < 4; ++i) atomAddF(&stats[DIM + tid * 4 + i], red[tid * 4 + i]);
  }
}

__global__ void bn_finalize_kernel(const float* __restrict__ stats,
                                   const float* __restrict__ gamma,
                                   const float* __restrict__ beta,
                                   float* __restrict__ scsh) {
  const int c = threadIdx.x;  // 128
  float mu  = stats[c] * (1.0f / N);
  float var = stats[DIM + c] * (1.0f / N) - mu * mu;
  float inv = rsqrtf(var + BN_EPS);
  float scale = gamma[c] * inv;
  scsh[c]       = scale;
  scsh[DIM + c] = beta[c] - mu * scale;
}

// ---------------- segment pooling over sorted batch -------------------------------

__global__ __launch_bounds__(256) void pool_kernel(const float* __restrict__ x1,
                                                   const int* __restrict__ batch,
                                                   float* __restrict__ pooled) {
  const int grp  = (blockIdx.x * blockDim.x + threadIdx.x) >> 5;  // 64-node chunk
  const int lane = threadIdx.x & 31;
  const int node0 = grp * 64;
  if (node0 >= N) return;
  const int end = (node0 + 64 < N) ? (node0 + 64) : N;
  float4 acc = {0, 0, 0, 0};
  int cur = batch[node0];
  for (int n = node0; n < end; ++n) {
    int b = batch[n];
    if (b != cur) {
      atomAddF(&pooled[(size_t)cur * DIM + lane * 4 + 0], acc.x);
      atomAddF(&pooled[(size_t)cur * DIM + lane * 4 + 1], acc.y);
      atomAddF(&pooled[(size_t)cur * DIM + lane * 4 + 2], acc.z);
      atomAddF(&pooled[(size_t)cur * DIM + lane * 4 + 3], acc.w);
      acc = {0, 0, 0, 0};
      cur = b;
    }
    float4 v = ((const float4*)x1)[(size_t)n * 32 + lane];
    acc.x += v.x; acc.y += v.y; acc.z += v.z; acc.w += v.w;
  }
  atomAddF(&pooled[(size_t)cur * DIM + lane * 4 + 0], acc.x);
  atomAddF(&pooled[(size_t)cur * DIM + lane * 4 + 1], acc.y);
  atomAddF(&pooled[(size_t)cur * DIM + lane * 4 + 2], acc.z);
  atomAddF(&pooled[(size_t)cur * DIM + lane * 4 + 3], acc.w);
}

// ---------------- final MLP + log_softmax -----------------------------------------

__global__ __launch_bounds__(128) void mlp_kernel(const float* __restrict__ pooled,
                                                  const float* __restrict__ W1,
                                                  const float* __restrict__ b1,
                                                  const float* __restrict__ W2,
                                                  const float* __restrict__ b2,
                                                  float* __restrict__ out) {
  const int gidx = blockIdx.x;
  const int t    = threadIdx.x;
  __shared__ float p[DIM], a1[DIM];
  p[t] = pooled[(size_t)gidx * DIM + t];
  __syncthreads();
  float acc = b1[t];
  for (int k = 0; k < DIM; ++k) acc = fmaf(p[k], W1[(size_t)k * DIM + t], acc);
  a1[t] = fmaxf(acc, 0.f);
  __syncthreads();
  if (t < OUTC) {
    float o = b2[t];
    for (int k = 0; k < DIM; ++k) o = fmaf(a1[k], W2[(size_t)k * OUTC + t], o);
    float m = o;
    for (int s = 8; s >= 1; s >>= 1) m = fmaxf(m, __shfl_xor(m, s, 16));
    float e = __expf(o - m);
    float se = e;
    for (int s = 8; s >= 1; s >>= 1) se += __shfl_xor(se, s, 16);
    out[(size_t)gidx * OUTC + t] = o - m - __logf(se);
  }
}

}  // namespace

extern "C" void kernel_launch(void* const* d_in, const int* in_sizes, int n_in,
                              void* d_out, int out_size, void* d_ws, size_t ws_size,
                              hipStream_t stream) {
  const float* x     = (const float*)d_in[0];
  const int*   ei    = (const int*)d_in[1];   // [2,E]: src then dst
  const int*   batch = (const int*)d_in[2];
  const float* W1_0  = (const float*)d_in[4];
  const float* b1_0  = (const float*)d_in[5];
  const float* g_0   = (const float*)d_in[6];
  const float* bt_0  = (const float*)d_in[7];
  const float* W2_0  = (const float*)d_in[8];
  const float* b2_0  = (const float*)d_in[9];
  const float* W1s   = (const float*)d_in[10];
  const float* b1s   = (const float*)d_in[11];
  const float* gs    = (const float*)d_in[12];
  const float* bts   = (const float*)d_in[13];
  const float* W2s   = (const float*)d_in[14];
  const float* b2s   = (const float*)d_in[15];
  const float* lin1W = (const float*)d_in[16];
  const float* lin1b = (const float*)d_in[17];
  const float* lin2W = (const float*)d_in[18];
  const float* lin2b = (const float*)d_in[19];

  float* out_ls = (float*)d_out;                 // [256,16]
  float* x1_out = (float*)d_out + NG * OUTC;     // [40000,128] — also ping-pong buf B

  // workspace carve (256B aligned)
  char* w = (char*)d_ws;
  auto alloc = [&](size_t bytes) -> void* {
    void* p = (void*)w;
    w += (bytes + 255) & ~(size_t)255;
    return p;
  };
  int*   deg    = (int*)alloc((size_t)N * 4);
  int*   rp     = (int*)alloc((size_t)(N + 1) * 4);
  int*   cursor = (int*)alloc((size_t)N * 4);
  int*   col    = (int*)alloc((size_t)E * 4);
  float* bufA   = (float*)alloc((size_t)N * DIM * 4);
  float* stats  = (float*)alloc((size_t)2 * DIM * 4);
  float* scsh   = (float*)alloc((size_t)2 * DIM * 4);
  float* pooled = (float*)alloc((size_t)NG * DIM * 4);

  const int* src = ei;
  const int* dst = ei + E;

  // ---- CSR build (reused by all 5 layers) ----
  zero_ints<<<(N + 255) / 256, 256, 0, stream>>>(deg, N);
  hist_kernel<<<E / 256, 256, 0, stream>>>(dst, deg);
  scan_kernel<<<1, 1024, 0, stream>>>(deg, rp);
  copy_ints<<<(N + 255) / 256, 256, 0, stream>>>(rp, cursor, N);
  fill_kernel<<<E / 256, 256, 0, stream>>>(src, dst, cursor, col);

  // ---- 5 GIN layers ----
  // parity: even layer idx: t=bufB(x1 region), h=bufA ; odd: t=bufA, h=bufB.
  // out = t's buffer, except layer 4 -> x1_out (== bufB, t dead by then).
  float* bufB = x1_out;
  const float* xin = x;
  for (int l = 0; l < 5; ++l) {
    float* t = (l & 1) ? bufA : bufB;
    float* h = (l & 1) ? bufB : bufA;
    float* o = (l == 4) ? x1_out : t;
    const float* W1 = (l == 0) ? W1_0 : W1s + (size_t)(l - 1) * DIM * DIM;
    const float* b1 = (l == 0) ? b1_0 : b1s + (size_t)(l - 1) * DIM;
    const float* gg = (l == 0) ? g_0  : gs  + (size_t)(l - 1) * DIM;
    const float* bb = (l == 0) ? bt_0 : bts + (size_t)(l - 1) * DIM;
    const float* W2 = (l == 0) ? W2_0 : W2s + (size_t)(l - 1) * DIM * DIM;
    const float* b2 = (l == 0) ? b2_0 : b2s + (size_t)(l - 1) * DIM;

    aggregate_kernel<<<(N * 32) / 256, 256, 0, stream>>>(xin, rp, col, t);
    gemm_k<0, 0><<<(N / 64) * 4, 64, 0, stream>>>(t, W1, b1, nullptr, h);
    hipMemsetAsync(stats, 0, 2 * DIM * sizeof(float), stream);
    bn_stats_kernel<<<256, 256, 0, stream>>>(h, stats);
    bn_finalize_kernel<<<1, DIM, 0, stream>>>(stats, gg, bb, scsh);
    gemm_k<1, 1><<<(N / 64) * 4, 64, 0, stream>>>(h, W2, b2, scsh, o);
    xin = o;
  }

  // ---- pooling + MLP head ----
  hipMemsetAsync(pooled, 0, (size_t)NG * DIM * sizeof(float), stream);
  {
    int groups = (N + 63) / 64;                 // 625
    int blocks = (groups * 32 + 255) / 256;     // 79
    pool_kernel<<<blocks, 256, 0, stream>>>(x1_out, batch, pooled);
  }
  mlp_kernel<<<NG, 128, 0, stream>>>(pooled, lin1W, lin1b, lin2W, lin2b, out_ls);
}